// Round 2
// baseline (741.596 us; speedup 1.0000x reference)
//
#include <hip/hip_runtime.h>
#include <math.h>

// B=4, T=2048, D=2048, K=8 -> S=9 sources per (b,t).
// Outputs concatenated in d_out: routed_hidden [B*T*D], weights [B*T*S], entropy [B*T].
constexpr int Bdim = 4;
constexpr int Tdim = 2048;
constexpr int Ddim = 2048;
constexpr int Kdim = 8;
constexpr int Sdim = Kdim + 1;      // 9
constexpr float EPSF = 1e-8f;
constexpr int THREADS = 512;        // 512 threads x 4 floats = 2048 = D
constexpr int NWAVES  = THREADS / 64;

// One workgroup per (b,t). Each thread holds one float4 per source (9 float4s,
// 36 VGPRs of payload). All 9 loads are issued before any dependent compute so
// the wave has 9 independent HBM transactions in flight (latency hiding), and
// the small footprint keeps occupancy high.
__global__ __launch_bounds__(THREADS) void bar_routed_kernel(
    const float* __restrict__ embedding,   // [B*T*D]
    const float* __restrict__ blocks,      // [K*B*T*D]
    const float* __restrict__ query,       // [D]
    const float* __restrict__ key_weight,  // [D]
    float* __restrict__ routed,            // [B*T*D]
    float* __restrict__ weights_out,       // [B*T*S]
    float* __restrict__ entropy_out)       // [B*T]
{
    const int bt  = blockIdx.x;           // 0 .. B*T-1
    const int tid = threadIdx.x;          // 0 .. 511
    const int d0  = tid * 4;

    // ---- Phase 1: issue ALL global loads before any dependent compute ----
    float4 v[Sdim];
    {
        const float* e = embedding + (size_t)bt * Ddim + d0;
        v[0] = *reinterpret_cast<const float4*>(e);
        #pragma unroll
        for (int s = 1; s < Sdim; ++s) {
            const float* p = blocks +
                ((size_t)(s - 1) * (Bdim * Tdim) + (size_t)bt) * (size_t)Ddim + d0;
            v[s] = *reinterpret_cast<const float4*>(p);
        }
    }
    const float4 q4 = *reinterpret_cast<const float4*>(query + d0);
    const float4 w4 = *reinterpret_cast<const float4*>(key_weight + d0);
    const float qw[4] = {q4.x * w4.x, q4.y * w4.y, q4.z * w4.z, q4.w * w4.w};

    // ---- Phase 2: per-source partial sum-of-squares and dot(src, q*w) ----
    float ss[Sdim];
    float dt[Sdim];
    #pragma unroll
    for (int s = 0; s < Sdim; ++s) {
        float s2, dd;
        s2 = v[s].x * v[s].x;           dd = v[s].x * qw[0];
        s2 = fmaf(v[s].y, v[s].y, s2);  dd = fmaf(v[s].y, qw[1], dd);
        s2 = fmaf(v[s].z, v[s].z, s2);  dd = fmaf(v[s].z, qw[2], dd);
        s2 = fmaf(v[s].w, v[s].w, s2);  dd = fmaf(v[s].w, qw[3], dd);
        ss[s] = s2;
        dt[s] = dd;
    }

    // ---- Phase 3: wave-64 butterfly, then cross-wave LDS reduction ----
    #pragma unroll
    for (int s = 0; s < Sdim; ++s) {
        #pragma unroll
        for (int off = 32; off >= 1; off >>= 1) {
            ss[s] += __shfl_xor(ss[s], off, 64);
            dt[s] += __shfl_xor(dt[s], off, 64);
        }
    }

    __shared__ float red_ss[NWAVES][Sdim];
    __shared__ float red_dt[NWAVES][Sdim];
    const int wave = tid >> 6;
    const int lane = tid & 63;
    if (lane == 0) {
        #pragma unroll
        for (int s = 0; s < Sdim; ++s) {
            red_ss[wave][s] = ss[s];
            red_dt[wave][s] = dt[s];
        }
    }
    __syncthreads();

    // ---- Phase 4: every thread computes the 9-way softmax redundantly ----
    float w[Sdim];
    float lmax = -1e30f;
    #pragma unroll
    for (int s = 0; s < Sdim; ++s) {
        float tss = 0.0f, tdt = 0.0f;
        #pragma unroll
        for (int k = 0; k < NWAVES; ++k) { tss += red_ss[k][s]; tdt += red_dt[k][s]; }
        const float logit = tdt * rsqrtf(tss * (1.0f / (float)Ddim) + EPSF);
        w[s] = logit;
        lmax = fmaxf(lmax, logit);
    }
    float esum = 0.0f;
    #pragma unroll
    for (int s = 0; s < Sdim; ++s) {
        w[s] = expf(w[s] - lmax);
        esum += w[s];
    }
    const float inv = 1.0f / esum;
    float ent = 0.0f;
    #pragma unroll
    for (int s = 0; s < Sdim; ++s) {
        w[s] *= inv;
        const float cw = fmaxf(w[s], 1e-12f);
        ent -= cw * logf(cw);
    }

    // ---- Phase 5: weighted combine from registers; coalesced float4 store ----
    float4 o;
    o.x = 0.0f; o.y = 0.0f; o.z = 0.0f; o.w = 0.0f;
    #pragma unroll
    for (int s = 0; s < Sdim; ++s) {
        o.x = fmaf(w[s], v[s].x, o.x);
        o.y = fmaf(w[s], v[s].y, o.y);
        o.z = fmaf(w[s], v[s].z, o.z);
        o.w = fmaf(w[s], v[s].w, o.w);
    }
    *reinterpret_cast<float4*>(routed + (size_t)bt * Ddim + d0) = o;

    if (tid < Sdim) weights_out[(size_t)bt * Sdim + tid] = w[tid];
    if (tid == 0)  entropy_out[bt] = ent;
}

extern "C" void kernel_launch(void* const* d_in, const int* in_sizes, int n_in,
                              void* d_out, int out_size, void* d_ws, size_t ws_size,
                              hipStream_t stream) {
    const float* embedding  = (const float*)d_in[0];
    const float* blocks     = (const float*)d_in[1];
    const float* query      = (const float*)d_in[2];
    const float* key_weight = (const float*)d_in[3];

    float* routed      = (float*)d_out;
    float* weights_out = routed + (size_t)Bdim * Tdim * Ddim;
    float* entropy_out = weights_out + (size_t)Bdim * Tdim * Sdim;

    dim3 grid(Bdim * Tdim);
    dim3 block(THREADS);
    bar_routed_kernel<<<grid, block, 0, stream>>>(
        embedding, blocks, query, key_weight, routed, weights_out, entropy_out);
}